// Round 8
// baseline (689.738 us; speedup 1.0000x reference)
//
#include <hip/hip_runtime.h>
#include <math.h>

#define NB   2048
#define NT   32
#define NTAU 1024
#define NMSG 512
#define NHID 1024
#define NV   128
#define MSZ  (NTAU * NMSG)   // 524288 elements in M

typedef __attribute__((ext_vector_type(8))) short  short8v;  // bf16x8 MFMA frag
typedef __attribute__((ext_vector_type(4))) float  f32x4;    // MFMA acc
typedef __attribute__((ext_vector_type(4))) float  f4v;      // vector float4

// ---- bf16 helpers (round-to-nearest-even) ----
__device__ inline unsigned short f2bf(float x) {
  unsigned u = __builtin_bit_cast(unsigned, x);
  u = (u + 0x7fff + ((u >> 16) & 1)) >> 16;
  return (unsigned short)u;
}
__device__ inline float bf2f(unsigned short h) {
  unsigned u = ((unsigned)h) << 16;
  return __builtin_bit_cast(float, u);
}

// Fragment-swizzled element offset for matrix X[R][K] consumed as a 16x16x32
// bf16 MFMA operand. Tile (r>>4, k>>5); within tile lane l holds 8 elems with
// k = 16*(j>>2) + (l>>4)*4 + (j&3)  (kappa; identical for A and B operands, so
// any error in kappa is a shared k-permutation and cancels in the product).
__device__ inline size_t frag_off(int r, int k, int K) {
  const int T = (r >> 4) * (K >> 5) + (k >> 5);
  const int l = (((k >> 2) & 3) << 4) | (r & 15);
  const int j = (((k >> 4) & 1) << 2) | (k & 3);
  return (size_t)T * 512 + (size_t)l * 8 + j;
}

// ---------------- fp32 GEMM, 64x64 tile, 4x4 per thread ----------------
// LOADT = 0 : C[i,j] = sum_k A[(kbase+k)*lda+i]*B[(kbase+k)*ldb+j]  (A^T B),
//             kbase = z*Kdim, C written at C + z*csz (split-K partials).
// LOADT = 1 : C[i,j] = sum_k A[i*lda+k]*B[j*ldb+k] + bias[j]  (fallback K1).
// blockIdx.y == prepY (z==0): mv/u/s0 side work. blockIdx.y == convY: rm->bf16
// hi/lo fragment-swizzled conversion (independent work, overlaps the GEMM).
template<int LOADT>
__global__ __launch_bounds__(256)
void gemm64(const float* __restrict__ A, const float* __restrict__ Bm,
            const float* __restrict__ bias, float* __restrict__ C,
            int Kdim, int lda, int ldb, int ldc, int csz,
            const float* __restrict__ pWq, const float* __restrict__ pbq,
            const float* __restrict__ pWk, const float* __restrict__ pbk,
            float* __restrict__ mv, float* __restrict__ u, float* __restrict__ s0,
            int prepY,
            const float* __restrict__ rmsrc, unsigned short* __restrict__ rmh,
            unsigned short* __restrict__ rml, int convY)
{
  __shared__ float As[16][68];
  __shared__ float Bs[16][68];
  const int tid = threadIdx.x;

  if ((int)blockIdx.y == convY) {
    // rm [2048x512] -> bf16 hi/lo, fragment-swizzled. 64 blocks x 32 rows.
    const int rowbase = ((int)blockIdx.x * 4 + (int)blockIdx.z) * 32;
    const int b = rowbase + (tid >> 3);
    const int kb = (tid & 7) * 64;
    #pragma unroll
    for (int i = 0; i < 16; ++i) {
      const int k0 = kb + i * 4;
      const float4 v = *(const float4*)&rmsrc[(size_t)b * NMSG + k0];
      ushort4 h, l;
      h.x = f2bf(v.x); l.x = f2bf(v.x - bf2f(h.x));
      h.y = f2bf(v.y); l.y = f2bf(v.y - bf2f(h.y));
      h.z = f2bf(v.z); l.z = f2bf(v.z - bf2f(h.z));
      h.w = f2bf(v.w); l.w = f2bf(v.w - bf2f(h.w));
      const size_t off = frag_off(b, k0, NMSG);
      *(ushort4*)(rmh + off) = h;
      *(ushort4*)(rml + off) = l;
    }
    return;
  }

  if ((int)blockIdx.y == prepY) {
    if (blockIdx.z != 0) return;
    // mv[c] = sum_h Wk[h,c]*bq[h];  u[m] = sum_h Wq[h,m]*bk[h];  s0 = bq.bk
    const int role = blockIdx.x;
    if (role < 4) {
      const int c = role * 256 + tid;
      float acc = 0.f;
      #pragma unroll 4
      for (int h = 0; h < NHID; ++h) acc += pWk[h * NTAU + c] * pbq[h];
      mv[c] = acc;
    } else if (role < 6) {
      const int m = (role - 4) * 256 + tid;
      float acc = 0.f;
      #pragma unroll 4
      for (int h = 0; h < NHID; ++h) acc += pWq[h * NMSG + m] * pbk[h];
      u[m] = acc;
    } else if (role == 6) {
      float acc = 0.f;
      for (int h = tid; h < NHID; h += 256) acc += pbq[h] * pbk[h];
      ((float*)As)[tid] = acc;
      __syncthreads();
      if (tid < 64) {
        float v = ((float*)As)[tid] + ((float*)As)[tid + 64] +
                  ((float*)As)[tid + 128] + ((float*)As)[tid + 192];
        #pragma unroll
        for (int off = 32; off; off >>= 1) v += __shfl_xor(v, off, 64);
        if (tid == 0) s0[0] = v;
      }
    }
    return;
  }

  const int tx = tid & 15, ty = tid >> 4;
  const int i0 = blockIdx.x * 64, j0 = blockIdx.y * 64;
  const int kbase = blockIdx.z * Kdim;
  float* Cw = C + (size_t)blockIdx.z * csz;
  float acc[4][4] = {};

  for (int k0 = 0; k0 < Kdim; k0 += 16) {
    #pragma unroll
    for (int q = 0; q < 4; ++q) {
      const int e = tid + 256 * q;
      if (LOADT == 0) {
        const int kk = e >> 6, r = e & 63;
        As[kk][r] = A[(size_t)(kbase + k0 + kk) * lda + (i0 + r)];
        Bs[kk][r] = Bm[(size_t)(kbase + k0 + kk) * ldb + (j0 + r)];
      } else {
        const int kk = e & 15, r = e >> 4;
        As[kk][r] = A[(size_t)(i0 + r) * lda + (k0 + kk)];
        Bs[kk][r] = Bm[(size_t)(j0 + r) * ldb + (k0 + kk)];
      }
    }
    __syncthreads();
    #pragma unroll
    for (int k = 0; k < 16; ++k) {
      // row stride 68*4=272 B is 16B-divisible; ty*4/tx*4 are 16B-aligned ->
      // these become ds_read_b128 (was 8x ds_read_b32).
      const float4 av = *(const float4*)&As[k][ty * 4];
      const float4 bv = *(const float4*)&Bs[k][tx * 4];
      const float a[4]  = {av.x, av.y, av.z, av.w};
      const float bb[4] = {bv.x, bv.y, bv.z, bv.w};
      #pragma unroll
      for (int i = 0; i < 4; ++i)
        #pragma unroll
        for (int j = 0; j < 4; ++j) acc[i][j] += a[i] * bb[j];
    }
    __syncthreads();
  }

  float bj[4] = {0.f, 0.f, 0.f, 0.f};
  if (bias) {
    #pragma unroll
    for (int j = 0; j < 4; ++j) bj[j] = bias[j0 + tx * 4 + j];
  }
  #pragma unroll
  for (int i = 0; i < 4; ++i) {
    float4 v;
    v.x = acc[i][0] + bj[0];
    v.y = acc[i][1] + bj[1];
    v.z = acc[i][2] + bj[2];
    v.w = acc[i][3] + bj[3];
    *(float4*)&Cw[(size_t)(i0 + ty * 4 + i) * ldc + (j0 + tx * 4)] = v;
  }
}

// ---- K0b: M = sum of 4 split-K partials -> bf16 hi/lo fragment-swizzled ----
__global__ __launch_bounds__(256)
void m_reduce_convert(const float* __restrict__ Mp, unsigned short* __restrict__ mh,
                      unsigned short* __restrict__ ml)
{
  const int f = ((int)blockIdx.x * 256 + (int)threadIdx.x) * 4;  // 512 blocks
  const int r = f >> 9, k0 = f & 511;
  float4 s = *(const float4*)&Mp[f];
  #pragma unroll
  for (int p = 1; p < 4; ++p) {
    const float4 t = *(const float4*)&Mp[(size_t)p * MSZ + f];
    s.x += t.x; s.y += t.y; s.z += t.z; s.w += t.w;
  }
  ushort4 h, l;
  h.x = f2bf(s.x); l.x = f2bf(s.x - bf2f(h.x));
  h.y = f2bf(s.y); l.y = f2bf(s.y - bf2f(h.y));
  h.z = f2bf(s.z); l.z = f2bf(s.z - bf2f(h.z));
  h.w = f2bf(s.w); l.w = f2bf(s.w - bf2f(h.w));
  const size_t off = frag_off(r, k0, NMSG);
  *(ushort4*)(mh + off) = h;
  *(ushort4*)(ml + off) = l;
}

// ---- K1: qk[b,c] = sum_m rm[b,m]*M[c,m] + mv[c], bf16-split MFMA ----
// Block 64(b) x 128(c), 8 waves = 2(b) x 4(c); wave = 2x2 16x16 tiles.
// 3 MFMA per tile pair per k-step: hi*hi + hi*lo + lo*hi (lo*lo ~2^-18, dropped).
__global__ __launch_bounds__(512)
void qk_mfma(const unsigned short* __restrict__ rh, const unsigned short* __restrict__ rl,
             const unsigned short* __restrict__ mh, const unsigned short* __restrict__ ml,
             const float* __restrict__ mv, float* __restrict__ qkout)
{
  const int tid = threadIdx.x, lane = tid & 63, wid = tid >> 6;
  const int wb = wid >> 2, wc = wid & 3;
  const int bt0 = (int)blockIdx.x * 4 + wb * 2;   // b tile idx (16-row units)
  const int ct0 = (int)blockIdx.y * 8 + wc * 2;   // c tile idx
  const int KT = NMSG / 32;                       // 16 k-steps

  f32x4 acc[2][2] = {};

  #pragma unroll 4
  for (int ks = 0; ks < KT; ++ks) {
    short8v ah[2], al[2], bh[2], bl[2];
    #pragma unroll
    for (int m = 0; m < 2; ++m) {
      const size_t off = ((size_t)(bt0 + m) * KT + ks) * 512 + lane * 8;
      ah[m] = *(const short8v*)(rh + off);
      al[m] = *(const short8v*)(rl + off);
    }
    #pragma unroll
    for (int n = 0; n < 2; ++n) {
      const size_t off = ((size_t)(ct0 + n) * KT + ks) * 512 + lane * 8;
      bh[n] = *(const short8v*)(mh + off);
      bl[n] = *(const short8v*)(ml + off);
    }
    #pragma unroll
    for (int m = 0; m < 2; ++m)
      #pragma unroll
      for (int n = 0; n < 2; ++n) {
        acc[m][n] = __builtin_amdgcn_mfma_f32_16x16x32_bf16(ah[m], bh[n], acc[m][n], 0, 0, 0);
        acc[m][n] = __builtin_amdgcn_mfma_f32_16x16x32_bf16(ah[m], bl[n], acc[m][n], 0, 0, 0);
        acc[m][n] = __builtin_amdgcn_mfma_f32_16x16x32_bf16(al[m], bh[n], acc[m][n], 0, 0, 0);
      }
  }

  // C/D layout (m89-verified): col = lane&15, row = (lane>>4)*4 + reg
  const int col = lane & 15, rowg = (lane >> 4) * 4;
  #pragma unroll
  for (int m = 0; m < 2; ++m)
    #pragma unroll
    for (int n = 0; n < 2; ++n) {
      const int c = (ct0 + n) * 16 + col;
      const float mvv = mv[c];
      #pragma unroll
      for (int r = 0; r < 4; ++r) {
        const int b = (bt0 + m) * 16 + rowg + r;
        qkout[(size_t)b * NTAU + c] = acc[m][n][r] + mvv;
      }
    }
}

// ---------------- fused: scores -> softmax -> ctx -> Wv*ctx + bv ----------------
// One block per b. tau[b] (32x1024 f32) read ONCE from HBM into registers
// (nontemporal: pure stream). Peak live VGPRs ~80 -> fits 128-cap of (512,4)
// => 2 blocks/CU, so the next block's tau loads overlap this block's compute.
__global__ __launch_bounds__(512, 4)
void fused_attn(const float* __restrict__ traj, const float* __restrict__ rm,
                const float* __restrict__ qk, const float* __restrict__ u,
                const float* __restrict__ s0p, const float* __restrict__ Wv,
                const float* __restrict__ bv, float* __restrict__ out)
{
  __shared__ __align__(16) float qks[NTAU];        // 4 KB   qk[b]
  __shared__ __align__(16) float wctx[8][NTAU];    // 32 KB  per-wave ctx partials
  __shared__ __align__(16) float ctx[NTAU];        // 4 KB   final ctx
  __shared__ float sc[NT];
  __shared__ float red[8];

  const int b = blockIdx.x;
  const int tid = threadIdx.x;
  const int lane = tid & 63, wid = tid >> 6;  // 8 waves

  // ---- tau rows for this wave -> registers (nontemporal stream) ----
  f4v tr[4][4];
  const float* tb = traj + (size_t)b * (NT * NTAU);
  #pragma unroll
  for (int tt = 0; tt < 4; ++tt)
    #pragma unroll
    for (int i = 0; i < 4; ++i)
      tr[tt][i] = __builtin_nontemporal_load(
          (const f4v*)&tb[(wid * 4 + tt) * NTAU + lane * 4 + 256 * i]);

  // ---- qk[b] -> LDS; qbk partial = rm[b].u ----
  *(float2*)&qks[tid * 2] = *(const float2*)&qk[(size_t)b * NTAU + tid * 2];
  float up = rm[(size_t)b * NMSG + tid] * u[tid];
  #pragma unroll
  for (int off = 32; off; off >>= 1) up += __shfl_xor(up, off, 64);
  if (lane == 0) red[wid] = up;
  const float s0v = s0p[0];

  __syncthreads();  // qks + red ready

  float qbk = s0v;
  #pragma unroll
  for (int w = 0; w < 8; ++w) qbk += red[w];

  // ---- scores: wave wid computes t = wid*4..wid*4+3 ----
  #pragma unroll
  for (int tt = 0; tt < 4; ++tt) {
    float d = 0.f;
    #pragma unroll
    for (int i = 0; i < 4; ++i) {
      const f4v a = tr[tt][i];
      const float4 qv = *(const float4*)&qks[lane * 4 + 256 * i];
      d += a.x * qv.x + a.y * qv.y + a.z * qv.z + a.w * qv.w;
    }
    #pragma unroll
    for (int off = 32; off; off >>= 1) d += __shfl_xor(d, off, 64);
    if (lane == 0) sc[wid * 4 + tt] = (d + qbk) * 0.03125f;
  }
  __syncthreads();

  // ---- softmax over 32 scores (redundant per thread; LDS broadcast reads) ----
  float mx = -1e30f;
  #pragma unroll
  for (int t = 0; t < NT; ++t) mx = fmaxf(mx, sc[t]);
  float ssum = 0.f;
  #pragma unroll
  for (int t = 0; t < NT; ++t) ssum += __expf(sc[t] - mx);
  const float rs = 1.f / ssum;

  // ---- per-wave ctx partial streamed straight from tr regs to LDS ----
  {
    const float e0 = __expf(sc[wid * 4 + 0] - mx) * rs;
    const float e1 = __expf(sc[wid * 4 + 1] - mx) * rs;
    const float e2 = __expf(sc[wid * 4 + 2] - mx) * rs;
    const float e3 = __expf(sc[wid * 4 + 3] - mx) * rs;
    #pragma unroll
    for (int i = 0; i < 4; ++i) {
      const f4v r = tr[0][i] * e0 + tr[1][i] * e1 + tr[2][i] * e2 + tr[3][i] * e3;
      *(f4v*)&wctx[wid][lane * 4 + 256 * i] = r;
    }
  }
  __syncthreads();

  // ---- cross-wave ctx reduce: thread owns cols tid*2, tid*2+1 ----
  float cx = 0.f, cy = 0.f;
  #pragma unroll
  for (int w = 0; w < 8; ++w) {
    const float2 v = *(const float2*)&wctx[w][tid * 2];
    cx += v.x; cy += v.y;
  }
  *(float2*)&ctx[tid * 2] = make_float2(cx, cy);
  __syncthreads();

  // ---- out[b,d] = Wv[d,:].ctx + bv[d]; wave wid does d = wid*16..+15 ----
  for (int r = 0; r < 16; ++r) {
    const int dd = wid * 16 + r;
    const float* wr = Wv + dd * NTAU;
    float p = 0.f;
    #pragma unroll
    for (int i = 0; i < 4; ++i) {
      const float4 w4 = *(const float4*)&wr[lane * 4 + 256 * i];
      const float4 c4 = *(const float4*)&ctx[lane * 4 + 256 * i];
      p += w4.x * c4.x + w4.y * c4.y + w4.z * c4.z + w4.w * c4.w;
    }
    #pragma unroll
    for (int off = 32; off; off >>= 1) p += __shfl_xor(p, off, 64);
    if (lane == 0) out[b * NV + dd] = p + bv[dd];
  }
}

extern "C" void kernel_launch(void* const* d_in, const int* in_sizes, int n_in,
                              void* d_out, int out_size, void* d_ws, size_t ws_size,
                              hipStream_t stream) {
  const float* traj = (const float*)d_in[0];  // [2048, 32768]
  const float* rm   = (const float*)d_in[1];  // [2048, 512]
  const float* Wq   = (const float*)d_in[2];  // [1024, 512]
  const float* bq   = (const float*)d_in[3];  // [1024]
  const float* Wk   = (const float*)d_in[4];  // [1024, 1024]
  const float* bk   = (const float*)d_in[5];  // [1024]
  const float* Wv   = (const float*)d_in[6];  // [128, 1024]
  const float* bv   = (const float*)d_in[7];  // [128]
  float* out = (float*)d_out;                 // [2048, 128]

  float* ws = (float*)d_ws;

  // split-MFMA layout (floats): Mp[4*MSZ] | qk[NB*NTAU] | mv,u,s0 | bf16 area
  const size_t oMp = 0;
  const size_t oQk = 4 * (size_t)MSZ;                 // 2,097,152
  const size_t oMv = oQk + (size_t)NB * NTAU;         // 4,194,304
  const size_t oU  = oMv + 1024;
  const size_t oS0 = oU + 512;
  const size_t oBf = oS0 + 16;                        // 16B aligned
  const size_t nBfU = 2 * (size_t)NB * NMSG + 2 * (size_t)MSZ;  // ushorts
  const size_t need_mfma = (oBf + (nBfU + 1) / 2) * 4;

  // CALIBRATION ROUND (resubmitted; rounds 6-7 never ran due to infra): run
  // the full pipeline TWICE per call (identical, deterministic work; second
  // pass overwrites the same results). The dur_us delta vs round 5 (501.2 us)
  // measures our true total kernel time, which harness fills otherwise mask.
  for (int rep = 0; rep < 2; ++rep) {
    if (ws_size >= need_mfma) {
      float* Mp = ws + oMp;
      float* qk = ws + oQk;
      float* mv = ws + oMv;
      float* u  = ws + oU;
      float* s0 = ws + oS0;
      unsigned short* rmh = (unsigned short*)(ws + oBf);
      unsigned short* rml = rmh + (size_t)NB * NMSG;
      unsigned short* mh  = rml + (size_t)NB * NMSG;
      unsigned short* ml  = mh + MSZ;

      // K0: M partials (4-way split-K) + prep(y==8) + rm bf16 convert (y==9)
      gemm64<0><<<dim3(16, 10, 4), 256, 0, stream>>>(
          Wk, Wq, nullptr, Mp, /*K=*/256, NTAU, NMSG, NMSG, /*csz=*/MSZ,
          Wq, bq, Wk, bk, mv, u, s0, /*prepY=*/8,
          rm, rmh, rml, /*convY=*/9);

      // K0b: M = sum partials -> bf16 hi/lo swizzled
      m_reduce_convert<<<512, 256, 0, stream>>>(Mp, mh, ml);

      // K1: qk = rm*M^T + mv via bf16-split MFMA
      qk_mfma<<<dim3(32, 8), 512, 0, stream>>>(rmh, rml, mh, ml, mv, qk);

      fused_attn<<<NB, 512, 0, stream>>>(traj, rm, qk, u, s0, Wv, bv, out);
    } else {
      // fallback: all-fp32, single-buffer M
      float* M_mat = ws;                 // 1024x512
      float* mv    = ws + MSZ;
      float* u     = mv + 1024;
      float* s0    = u + 512;
      float* qk    = s0 + 16;            // 2048*1024

      gemm64<0><<<dim3(16, 9, 1), 256, 0, stream>>>(
          Wk, Wq, nullptr, M_mat, /*K=*/NHID, NTAU, NMSG, NMSG, /*csz=*/0,
          Wq, bq, Wk, bk, mv, u, s0, /*prepY=*/8,
          nullptr, nullptr, nullptr, /*convY=*/-1);

      gemm64<1><<<dim3(32, 16, 1), 256, 0, stream>>>(
          rm, M_mat, mv, qk, /*K=*/NMSG, NMSG, NMSG, NTAU, /*csz=*/0,
          nullptr, nullptr, nullptr, nullptr, nullptr, nullptr, nullptr, /*prepY=*/-1,
          nullptr, nullptr, nullptr, /*convY=*/-1);

      fused_attn<<<NB, 512, 0, stream>>>(traj, rm, qk, u, s0, Wv, bv, out);
    }
  }
}

// Round 10
// 447.427 us; speedup vs baseline: 1.5416x; 1.5416x over previous
//
#include <hip/hip_runtime.h>
#include <math.h>

#define NB   2048
#define NT   32
#define NTAU 1024
#define NMSG 512
#define NHID 1024
#define NV   128
#define MSZ  (NTAU * NMSG)   // 524288 elements in M

typedef __attribute__((ext_vector_type(8))) short  short8v;  // bf16x8 MFMA frag
typedef __attribute__((ext_vector_type(4))) float  f32x4;    // MFMA acc
typedef __attribute__((ext_vector_type(4))) float  f4v;      // vector float4

// ---- bf16 helpers (round-to-nearest-even) ----
__device__ inline unsigned short f2bf(float x) {
  unsigned u = __builtin_bit_cast(unsigned, x);
  u = (u + 0x7fff + ((u >> 16) & 1)) >> 16;
  return (unsigned short)u;
}
__device__ inline float bf2f(unsigned short h) {
  unsigned u = ((unsigned)h) << 16;
  return __builtin_bit_cast(float, u);
}

// Fragment-swizzled element offset for matrix X[R][K] consumed as a 16x16x32
// bf16 MFMA operand. kappa identical for A and B operands, so any error in
// kappa is a shared k-permutation and cancels in the product.
__device__ inline size_t frag_off(int r, int k, int K) {
  const int T = (r >> 4) * (K >> 5) + (k >> 5);
  const int l = (((k >> 2) & 3) << 4) | (r & 15);
  const int j = (((k >> 4) & 1) << 2) | (k & 3);
  return (size_t)T * 512 + (size_t)l * 8 + j;
}

// ---------------- fp32 GEMM, 64x64 tile, 4x4 per thread ----------------
// LOADT = 0 : C[i,j] = sum_k A[(kbase+k)*lda+i]*B[(kbase+k)*ldb+j]  (A^T B),
//             kbase = z*Kdim, C written at C + z*csz (split-K partials).
// LOADT = 1 : C[i,j] = sum_k A[i*lda+k]*B[j*ldb+k] + bias[j]  (fallback K1).
// blockIdx.y == prepY (z==0): mv/u/s0 side work. blockIdx.y == convY: rm->bf16
// hi/lo fragment-swizzled conversion (independent work, overlaps the GEMM).
template<int LOADT>
__global__ __launch_bounds__(256)
void gemm64(const float* __restrict__ A, const float* __restrict__ Bm,
            const float* __restrict__ bias, float* __restrict__ C,
            int Kdim, int lda, int ldb, int ldc, int csz,
            const float* __restrict__ pWq, const float* __restrict__ pbq,
            const float* __restrict__ pWk, const float* __restrict__ pbk,
            float* __restrict__ mv, float* __restrict__ u, float* __restrict__ s0,
            int prepY,
            const float* __restrict__ rmsrc, unsigned short* __restrict__ rmh,
            unsigned short* __restrict__ rml, int convY)
{
  __shared__ float As[16][68];
  __shared__ float Bs[16][68];
  const int tid = threadIdx.x;

  if ((int)blockIdx.y == convY) {
    // rm [2048x512] -> bf16 hi/lo, fragment-swizzled. 64 blocks x 32 rows.
    const int rowbase = ((int)blockIdx.x * 4 + (int)blockIdx.z) * 32;
    const int b = rowbase + (tid >> 3);
    const int kb = (tid & 7) * 64;
    #pragma unroll
    for (int i = 0; i < 16; ++i) {
      const int k0 = kb + i * 4;
      const float4 v = *(const float4*)&rmsrc[(size_t)b * NMSG + k0];
      ushort4 h, l;
      h.x = f2bf(v.x); l.x = f2bf(v.x - bf2f(h.x));
      h.y = f2bf(v.y); l.y = f2bf(v.y - bf2f(h.y));
      h.z = f2bf(v.z); l.z = f2bf(v.z - bf2f(h.z));
      h.w = f2bf(v.w); l.w = f2bf(v.w - bf2f(h.w));
      const size_t off = frag_off(b, k0, NMSG);
      *(ushort4*)(rmh + off) = h;
      *(ushort4*)(rml + off) = l;
    }
    return;
  }

  if ((int)blockIdx.y == prepY) {
    if (blockIdx.z != 0) return;
    // mv[c] = sum_h Wk[h,c]*bq[h];  u[m] = sum_h Wq[h,m]*bk[h];  s0 = bq.bk
    // unroll 16 -> 16 outstanding L2 loads (latency-bound matvec fix).
    const int role = blockIdx.x;
    if (role < 4) {
      const int c = role * 256 + tid;
      float acc = 0.f;
      #pragma unroll 16
      for (int h = 0; h < NHID; ++h) acc += pWk[h * NTAU + c] * pbq[h];
      mv[c] = acc;
    } else if (role < 6) {
      const int m = (role - 4) * 256 + tid;
      float acc = 0.f;
      #pragma unroll 16
      for (int h = 0; h < NHID; ++h) acc += pWq[h * NMSG + m] * pbk[h];
      u[m] = acc;
    } else if (role == 6) {
      float acc = 0.f;
      for (int h = tid; h < NHID; h += 256) acc += pbq[h] * pbk[h];
      ((float*)As)[tid] = acc;
      __syncthreads();
      if (tid < 64) {
        float v = ((float*)As)[tid] + ((float*)As)[tid + 64] +
                  ((float*)As)[tid + 128] + ((float*)As)[tid + 192];
        #pragma unroll
        for (int off = 32; off; off >>= 1) v += __shfl_xor(v, off, 64);
        if (tid == 0) s0[0] = v;
      }
    }
    return;
  }

  const int tx = tid & 15, ty = tid >> 4;
  const int i0 = blockIdx.x * 64, j0 = blockIdx.y * 64;
  const int kbase = blockIdx.z * Kdim;
  float* Cw = C + (size_t)blockIdx.z * csz;
  float acc[4][4] = {};

  for (int k0 = 0; k0 < Kdim; k0 += 16) {
    #pragma unroll
    for (int q = 0; q < 4; ++q) {
      const int e = tid + 256 * q;
      if (LOADT == 0) {
        const int kk = e >> 6, r = e & 63;
        As[kk][r] = A[(size_t)(kbase + k0 + kk) * lda + (i0 + r)];
        Bs[kk][r] = Bm[(size_t)(kbase + k0 + kk) * ldb + (j0 + r)];
      } else {
        const int kk = e & 15, r = e >> 4;
        As[kk][r] = A[(size_t)(i0 + r) * lda + (k0 + kk)];
        Bs[kk][r] = Bm[(size_t)(j0 + r) * ldb + (k0 + kk)];
      }
    }
    __syncthreads();
    #pragma unroll
    for (int k = 0; k < 16; ++k) {
      const float4 av = *(const float4*)&As[k][ty * 4];
      const float4 bv = *(const float4*)&Bs[k][tx * 4];
      const float a[4]  = {av.x, av.y, av.z, av.w};
      const float bb[4] = {bv.x, bv.y, bv.z, bv.w};
      #pragma unroll
      for (int i = 0; i < 4; ++i)
        #pragma unroll
        for (int j = 0; j < 4; ++j) acc[i][j] += a[i] * bb[j];
    }
    __syncthreads();
  }

  float bj[4] = {0.f, 0.f, 0.f, 0.f};
  if (bias) {
    #pragma unroll
    for (int j = 0; j < 4; ++j) bj[j] = bias[j0 + tx * 4 + j];
  }
  #pragma unroll
  for (int i = 0; i < 4; ++i) {
    float4 v;
    v.x = acc[i][0] + bj[0];
    v.y = acc[i][1] + bj[1];
    v.z = acc[i][2] + bj[2];
    v.w = acc[i][3] + bj[3];
    *(float4*)&Cw[(size_t)(i0 + ty * 4 + i) * ldc + (j0 + tx * 4)] = v;
  }
}

// ---- K0b: M = sum of 4 split-K partials -> bf16 hi/lo fragment-swizzled ----
__global__ __launch_bounds__(256)
void m_reduce_convert(const float* __restrict__ Mp, unsigned short* __restrict__ mh,
                      unsigned short* __restrict__ ml)
{
  const int f = ((int)blockIdx.x * 256 + (int)threadIdx.x) * 4;  // 512 blocks
  const int r = f >> 9, k0 = f & 511;
  float4 s = *(const float4*)&Mp[f];
  #pragma unroll
  for (int p = 1; p < 4; ++p) {
    const float4 t = *(const float4*)&Mp[(size_t)p * MSZ + f];
    s.x += t.x; s.y += t.y; s.z += t.z; s.w += t.w;
  }
  ushort4 h, l;
  h.x = f2bf(s.x); l.x = f2bf(s.x - bf2f(h.x));
  h.y = f2bf(s.y); l.y = f2bf(s.y - bf2f(h.y));
  h.z = f2bf(s.z); l.z = f2bf(s.z - bf2f(h.z));
  h.w = f2bf(s.w); l.w = f2bf(s.w - bf2f(h.w));
  const size_t off = frag_off(r, k0, NMSG);
  *(ushort4*)(mh + off) = h;
  *(ushort4*)(ml + off) = l;
}

// ---- K1: qk[b,c] = sum_m rm[b,m]*M[c,m] + mv[c], bf16-split MFMA ----
__global__ __launch_bounds__(512)
void qk_mfma(const unsigned short* __restrict__ rh, const unsigned short* __restrict__ rl,
             const unsigned short* __restrict__ mh, const unsigned short* __restrict__ ml,
             const float* __restrict__ mv, float* __restrict__ qkout)
{
  const int tid = threadIdx.x, lane = tid & 63, wid = tid >> 6;
  const int wb = wid >> 2, wc = wid & 3;
  const int bt0 = (int)blockIdx.x * 4 + wb * 2;   // b tile idx (16-row units)
  const int ct0 = (int)blockIdx.y * 8 + wc * 2;   // c tile idx
  const int KT = NMSG / 32;                       // 16 k-steps

  f32x4 acc[2][2] = {};

  #pragma unroll 4
  for (int ks = 0; ks < KT; ++ks) {
    short8v ah[2], al[2], bh[2], bl[2];
    #pragma unroll
    for (int m = 0; m < 2; ++m) {
      const size_t off = ((size_t)(bt0 + m) * KT + ks) * 512 + lane * 8;
      ah[m] = *(const short8v*)(rh + off);
      al[m] = *(const short8v*)(rl + off);
    }
    #pragma unroll
    for (int n = 0; n < 2; ++n) {
      const size_t off = ((size_t)(ct0 + n) * KT + ks) * 512 + lane * 8;
      bh[n] = *(const short8v*)(mh + off);
      bl[n] = *(const short8v*)(ml + off);
    }
    #pragma unroll
    for (int m = 0; m < 2; ++m)
      #pragma unroll
      for (int n = 0; n < 2; ++n) {
        acc[m][n] = __builtin_amdgcn_mfma_f32_16x16x32_bf16(ah[m], bh[n], acc[m][n], 0, 0, 0);
        acc[m][n] = __builtin_amdgcn_mfma_f32_16x16x32_bf16(ah[m], bl[n], acc[m][n], 0, 0, 0);
        acc[m][n] = __builtin_amdgcn_mfma_f32_16x16x32_bf16(al[m], bh[n], acc[m][n], 0, 0, 0);
      }
  }

  // C/D layout (m89-verified): col = lane&15, row = (lane>>4)*4 + reg
  const int col = lane & 15, rowg = (lane >> 4) * 4;
  #pragma unroll
  for (int m = 0; m < 2; ++m)
    #pragma unroll
    for (int n = 0; n < 2; ++n) {
      const int c = (ct0 + n) * 16 + col;
      const float mvv = mv[c];
      #pragma unroll
      for (int r = 0; r < 4; ++r) {
        const int b = (bt0 + m) * 16 + rowg + r;
        qkout[(size_t)b * NTAU + c] = acc[m][n][r] + mvv;
      }
    }
}

// ---------------- fused: scores -> softmax -> ctx -> global CTX ----------------
// One block per b. tau[b] read ONCE from HBM into registers (nontemporal).
// ctx[b] is written to global; the Wv projection moved to ctx_gemm (saves
// 1 GB of per-block L2 Wv traffic). LDS ~36 KB, ~90 VGPR -> 2 blocks/CU.
__global__ __launch_bounds__(512, 4)
void fused_attn(const float* __restrict__ traj, const float* __restrict__ rm,
                const float* __restrict__ qk, const float* __restrict__ u,
                const float* __restrict__ s0p, float* __restrict__ ctxg)
{
  __shared__ __align__(16) float qks[NTAU];        // 4 KB   qk[b]
  __shared__ __align__(16) float wctx[8][NTAU];    // 32 KB  per-wave ctx partials
  __shared__ float sc[NT];
  __shared__ float red[8];

  const int b = blockIdx.x;
  const int tid = threadIdx.x;
  const int lane = tid & 63, wid = tid >> 6;  // 8 waves

  // ---- tau rows for this wave -> registers (nontemporal stream) ----
  f4v tr[4][4];
  const float* tb = traj + (size_t)b * (NT * NTAU);
  #pragma unroll
  for (int tt = 0; tt < 4; ++tt)
    #pragma unroll
    for (int i = 0; i < 4; ++i)
      tr[tt][i] = __builtin_nontemporal_load(
          (const f4v*)&tb[(wid * 4 + tt) * NTAU + lane * 4 + 256 * i]);

  // ---- qk[b] -> LDS; qbk partial = rm[b].u ----
  *(float2*)&qks[tid * 2] = *(const float2*)&qk[(size_t)b * NTAU + tid * 2];
  float up = rm[(size_t)b * NMSG + tid] * u[tid];
  #pragma unroll
  for (int off = 32; off; off >>= 1) up += __shfl_xor(up, off, 64);
  if (lane == 0) red[wid] = up;
  const float s0v = s0p[0];

  __syncthreads();  // qks + red ready (vmcnt drained)

  float qbk = s0v;
  #pragma unroll
  for (int w = 0; w < 8; ++w) qbk += red[w];

  // ---- scores: wave wid computes t = wid*4..wid*4+3 ----
  #pragma unroll
  for (int tt = 0; tt < 4; ++tt) {
    float d = 0.f;
    #pragma unroll
    for (int i = 0; i < 4; ++i) {
      const f4v a = tr[tt][i];
      const float4 qv = *(const float4*)&qks[lane * 4 + 256 * i];
      d += a.x * qv.x + a.y * qv.y + a.z * qv.z + a.w * qv.w;
    }
    #pragma unroll
    for (int off = 32; off; off >>= 1) d += __shfl_xor(d, off, 64);
    if (lane == 0) sc[wid * 4 + tt] = (d + qbk) * 0.03125f;
  }
  __syncthreads();

  // ---- softmax over 32 scores (redundant per thread; LDS broadcast reads) ----
  float mx = -1e30f;
  #pragma unroll
  for (int t = 0; t < NT; ++t) mx = fmaxf(mx, sc[t]);
  float ssum = 0.f;
  #pragma unroll
  for (int t = 0; t < NT; ++t) ssum += __expf(sc[t] - mx);
  const float rs = 1.f / ssum;

  // ---- per-wave ctx partial streamed straight from tr regs to LDS ----
  {
    const float e0 = __expf(sc[wid * 4 + 0] - mx) * rs;
    const float e1 = __expf(sc[wid * 4 + 1] - mx) * rs;
    const float e2 = __expf(sc[wid * 4 + 2] - mx) * rs;
    const float e3 = __expf(sc[wid * 4 + 3] - mx) * rs;
    #pragma unroll
    for (int i = 0; i < 4; ++i) {
      const f4v r = tr[0][i] * e0 + tr[1][i] * e1 + tr[2][i] * e2 + tr[3][i] * e3;
      *(f4v*)&wctx[wid][lane * 4 + 256 * i] = r;
    }
  }
  __syncthreads();

  // ---- cross-wave ctx reduce -> global CTX[b] (coalesced float2) ----
  float cx = 0.f, cy = 0.f;
  #pragma unroll
  for (int w = 0; w < 8; ++w) {
    const float2 v = *(const float2*)&wctx[w][tid * 2];
    cx += v.x; cy += v.y;
  }
  *(float2*)&ctxg[(size_t)b * NTAU + tid * 2] = make_float2(cx, cy);
}

// ---- K3: out = CTX * Wv^T + bv, fp32 tiled 32x32, grid (64,4) ----
// Wv traffic: 128 KB/block x 256 blocks = 32 MB (vs 1 GB when fused).
__global__ __launch_bounds__(256)
void ctx_gemm(const float* __restrict__ ctx, const float* __restrict__ Wv,
              const float* __restrict__ bv, float* __restrict__ out)
{
  __shared__ float As[32][36];
  __shared__ float Bs[32][36];
  const int tid = threadIdx.x;
  const int i0 = (int)blockIdx.x * 32;   // b rows
  const int j0 = (int)blockIdx.y * 32;   // d cols
  const int ti = (tid >> 4) * 2, tj = (tid & 15) * 2;

  float a00 = 0.f, a01 = 0.f, a10 = 0.f, a11 = 0.f;
  const int lrow = tid >> 3, lk = (tid & 7) * 4;

  for (int k0 = 0; k0 < NTAU; k0 += 32) {
    *(float4*)&As[lrow][lk] = *(const float4*)&ctx[(size_t)(i0 + lrow) * NTAU + k0 + lk];
    *(float4*)&Bs[lrow][lk] = *(const float4*)&Wv[(size_t)(j0 + lrow) * NTAU + k0 + lk];
    __syncthreads();
    #pragma unroll
    for (int kq = 0; kq < 8; ++kq) {
      const float4 x0 = *(const float4*)&As[ti][kq * 4];
      const float4 x1 = *(const float4*)&As[ti + 1][kq * 4];
      const float4 y0 = *(const float4*)&Bs[tj][kq * 4];
      const float4 y1 = *(const float4*)&Bs[tj + 1][kq * 4];
      a00 += x0.x * y0.x + x0.y * y0.y + x0.z * y0.z + x0.w * y0.w;
      a01 += x0.x * y1.x + x0.y * y1.y + x0.z * y1.z + x0.w * y1.w;
      a10 += x1.x * y0.x + x1.y * y0.y + x1.z * y0.z + x1.w * y0.w;
      a11 += x1.x * y1.x + x1.y * y1.y + x1.z * y1.z + x1.w * y1.w;
    }
    __syncthreads();
  }

  const float b0 = bv[j0 + tj], b1 = bv[j0 + tj + 1];
  *(float2*)&out[(size_t)(i0 + ti) * NV + (j0 + tj)]     = make_float2(a00 + b0, a01 + b1);
  *(float2*)&out[(size_t)(i0 + ti + 1) * NV + (j0 + tj)] = make_float2(a10 + b0, a11 + b1);
}

extern "C" void kernel_launch(void* const* d_in, const int* in_sizes, int n_in,
                              void* d_out, int out_size, void* d_ws, size_t ws_size,
                              hipStream_t stream) {
  const float* traj = (const float*)d_in[0];  // [2048, 32768]
  const float* rm   = (const float*)d_in[1];  // [2048, 512]
  const float* Wq   = (const float*)d_in[2];  // [1024, 512]
  const float* bq   = (const float*)d_in[3];  // [1024]
  const float* Wk   = (const float*)d_in[4];  // [1024, 1024]
  const float* bk   = (const float*)d_in[5];  // [1024]
  const float* Wv   = (const float*)d_in[6];  // [128, 1024]
  const float* bv   = (const float*)d_in[7];  // [128]
  float* out = (float*)d_out;                 // [2048, 128]

  float* ws = (float*)d_ws;

  // layout (floats): Mp[4*MSZ] (reused as CTX after K0b) | qk | mv,u,s0 | bf16
  const size_t oMp = 0;                               // 4*MSZ = 2,097,152 = NB*NTAU
  const size_t oQk = 4 * (size_t)MSZ;
  const size_t oMv = oQk + (size_t)NB * NTAU;
  const size_t oU  = oMv + 1024;
  const size_t oS0 = oU + 512;
  const size_t oBf = oS0 + 16;
  const size_t nBfU = 2 * (size_t)NB * NMSG + 2 * (size_t)MSZ;  // ushorts
  const size_t need_mfma = (oBf + (nBfU + 1) / 2) * 4;

  if (ws_size >= need_mfma) {
    float* Mp  = ws + oMp;
    float* ctx = ws + oMp;   // Mp dead after K0b; exact size match (2M floats)
    float* qk  = ws + oQk;
    float* mv  = ws + oMv;
    float* u   = ws + oU;
    float* s0  = ws + oS0;
    unsigned short* rmh = (unsigned short*)(ws + oBf);
    unsigned short* rml = rmh + (size_t)NB * NMSG;
    unsigned short* mh  = rml + (size_t)NB * NMSG;
    unsigned short* ml  = mh + MSZ;

    // K0: M partials (4-way split-K) + prep(y==8) + rm bf16 convert (y==9)
    gemm64<0><<<dim3(16, 10, 4), 256, 0, stream>>>(
        Wk, Wq, nullptr, Mp, /*K=*/256, NTAU, NMSG, NMSG, /*csz=*/MSZ,
        Wq, bq, Wk, bk, mv, u, s0, /*prepY=*/8,
        rm, rmh, rml, /*convY=*/9);

    // K0b: M = sum partials -> bf16 hi/lo swizzled
    m_reduce_convert<<<512, 256, 0, stream>>>(Mp, mh, ml);

    // K1: qk = rm*M^T + mv via bf16-split MFMA
    qk_mfma<<<dim3(32, 8), 512, 0, stream>>>(rmh, rml, mh, ml, mv, qk);

    // K2: scores/softmax/ctx (tau streamed once)
    fused_attn<<<NB, 512, 0, stream>>>(traj, rm, qk, u, s0, ctx);

    // K3: out = CTX*Wv^T + bv
    ctx_gemm<<<dim3(64, 4), 256, 0, stream>>>(ctx, Wv, bv, out);
  } else {
    // fallback: all-fp32, single-buffer M
    float* M_mat = ws;                 // 1024x512
    float* mv    = ws + MSZ;
    float* u     = mv + 1024;
    float* s0    = u + 512;
    float* qk    = s0 + 16;            // 2048*1024
    float* ctx   = qk + (size_t)NB * NTAU;

    gemm64<0><<<dim3(16, 9, 1), 256, 0, stream>>>(
        Wk, Wq, nullptr, M_mat, /*K=*/NHID, NTAU, NMSG, NMSG, /*csz=*/0,
        Wq, bq, Wk, bk, mv, u, s0, /*prepY=*/8,
        nullptr, nullptr, nullptr, /*convY=*/-1);

    gemm64<1><<<dim3(32, 16, 1), 256, 0, stream>>>(
        rm, M_mat, mv, qk, /*K=*/NMSG, NMSG, NMSG, NTAU, /*csz=*/0,
        nullptr, nullptr, nullptr, nullptr, nullptr, nullptr, nullptr, /*prepY=*/-1,
        nullptr, nullptr, nullptr, /*convY=*/-1);

    fused_attn<<<NB, 512, 0, stream>>>(traj, rm, qk, u, s0, ctx);
    ctx_gemm<<<dim3(64, 4), 256, 0, stream>>>(ctx, Wv, bv, out);
  }
}